// Round 1
// baseline (530.867 us; speedup 1.0000x reference)
//
#include <hip/hip_runtime.h>

#define IMG_H 2048
#define IMG_W 2048
#define NCH 3
#define BLK 4
#define NK 1024
#define DD 48              // BLK*BLK*NCH
#define WB (IMG_W / BLK)   // 512
#define HB (IMG_H / BLK)   // 512
#define NL (WB * HB)       // 262144

// Kernel 0: cnorm[k] = sum_j cb[k][j]^2  (sequential fp32 FMA)
__global__ void vq_cnorm_kernel(const float* __restrict__ cb, float* __restrict__ cnorm) {
    int k = blockIdx.x * blockDim.x + threadIdx.x;
    if (k >= NK) return;
    const float* row = cb + k * DD;
    float s = 0.0f;
#pragma unroll
    for (int j = 0; j < DD; ++j) s = fmaf(row[j], row[j], s);
    cnorm[k] = s;
}

// Main kernel: one thread per 4x4 image block.
__global__ __launch_bounds__(256) void vq_main_kernel(const float* __restrict__ img,
                                                      const float* __restrict__ cb,
                                                      const float* __restrict__ cnorm,
                                                      float* __restrict__ out) {
    const int l = blockIdx.x * blockDim.x + threadIdx.x;   // block id, < NL
    const int by = l / WB;
    const int bx = l - by * WB;

    // Load the 4x4x3 block into registers. Per row: 12 contiguous floats.
    float x[DD];
    const float* base = img + ((size_t)(by * BLK) * IMG_W + bx * BLK) * NCH;
#pragma unroll
    for (int r = 0; r < BLK; ++r) {
        const float4 a  = *(const float4*)(base + (size_t)r * IMG_W * NCH + 0);
        const float4 b  = *(const float4*)(base + (size_t)r * IMG_W * NCH + 4);
        const float4 c4 = *(const float4*)(base + (size_t)r * IMG_W * NCH + 8);
        x[r * 12 + 0] = a.x;  x[r * 12 + 1] = a.y;  x[r * 12 + 2]  = a.z;  x[r * 12 + 3]  = a.w;
        x[r * 12 + 4] = b.x;  x[r * 12 + 5] = b.y;  x[r * 12 + 6]  = b.z;  x[r * 12 + 7]  = b.w;
        x[r * 12 + 8] = c4.x; x[r * 12 + 9] = c4.y; x[r * 12 + 10] = c4.z; x[r * 12 + 11] = c4.w;
    }

    // xnorm = sum x^2 (sequential FMA)
    float xnorm = 0.0f;
#pragma unroll
    for (int j = 0; j < DD; ++j) xnorm = fmaf(x[j], x[j], xnorm);

    // Brute-force argmin over 1024 codes. Codebook address is wave-uniform ->
    // SMEM (s_load) + v_fma with SGPR operand.
    float best = __builtin_inff();
    int bestk = 0;
    for (int k = 0; k < NK; ++k) {
        const float* ck = cb + k * DD;
        float dot = 0.0f;
#pragma unroll
        for (int j = 0; j < DD; ++j) dot = fmaf(x[j], ck[j], dot);
        // Match reference rounding: t = 2*dot (exact), s = xnorm - t, d = s + cnorm[k]
        const float d = (xnorm - 2.0f * dot) + cnorm[k];
        const bool lt = d < best;          // strict <: first-occurrence argmin
        best  = lt ? d : best;
        bestk = lt ? k : bestk;
    }

    // Gather chosen code and scatter back to image layout.
    const float* q = cb + bestk * DD;
    float* obase = out + ((size_t)(by * BLK) * IMG_W + bx * BLK) * NCH;
#pragma unroll
    for (int r = 0; r < BLK; ++r) {
        const float4 a  = *(const float4*)(q + r * 12 + 0);
        const float4 b  = *(const float4*)(q + r * 12 + 4);
        const float4 c4 = *(const float4*)(q + r * 12 + 8);
        *(float4*)(obase + (size_t)r * IMG_W * NCH + 0) = a;
        *(float4*)(obase + (size_t)r * IMG_W * NCH + 4) = b;
        *(float4*)(obase + (size_t)r * IMG_W * NCH + 8) = c4;
    }
}

extern "C" void kernel_launch(void* const* d_in, const int* in_sizes, int n_in,
                              void* d_out, int out_size, void* d_ws, size_t ws_size,
                              hipStream_t stream) {
    const float* img = (const float*)d_in[0];   // (2048, 2048, 3) fp32
    const float* cb  = (const float*)d_in[1];   // (1024, 16, 3) fp32
    float* out = (float*)d_out;                 // (2048, 2048, 3) fp32
    float* cnorm = (float*)d_ws;                // 1024 floats

    vq_cnorm_kernel<<<(NK + 255) / 256, 256, 0, stream>>>(cb, cnorm);
    vq_main_kernel<<<NL / 256, 256, 0, stream>>>(img, cb, cnorm, out);
}

// Round 2
// 473.729 us; speedup vs baseline: 1.1206x; 1.1206x over previous
//
#include <hip/hip_runtime.h>

#define IMG_W 2048
#define NCH 3
#define BLK 4
#define NK 1024
#define DD 48              // BLK*BLK*NCH
#define WB 512             // blocks per image row
#define HB 512
#define NL (WB * HB)       // 262144 blocks
#define PPR (WB / 2)       // 256 block-pairs per row

// Kernel 0: cnorm[k] = sum_j cb[k][j]^2  (sequential fp32 FMA)
__global__ void vq_cnorm_kernel(const float* __restrict__ cb, float* __restrict__ cnorm) {
    int k = blockIdx.x * blockDim.x + threadIdx.x;
    if (k >= NK) return;
    const float* row = cb + k * DD;
    float s = 0.0f;
#pragma unroll
    for (int j = 0; j < DD; ++j) s = fmaf(row[j], row[j], s);
    cnorm[k] = s;
}

// Main kernel: one thread per PAIR of adjacent 4x4 blocks (M=2),
// inner loop processes 2 codes at a time (N=2) -> 4 independent FMA chains.
__global__ __launch_bounds__(256, 2) void vq_main_kernel(const float* __restrict__ img,
                                                         const float* __restrict__ cb,
                                                         const float* __restrict__ cnorm,
                                                         float* __restrict__ out) {
    const int t   = blockIdx.x * blockDim.x + threadIdx.x;   // pair id, < NL/2
    const int by  = t >> 8;          // / PPR
    const int px  = t & 255;         // % PPR
    const int bx0 = px * 2;          // left block of the pair

    // Load both 4x4x3 blocks into registers: 24 contiguous floats per row.
    float xa[DD], xb[DD];
    const float* base = img + ((size_t)by * BLK * IMG_W + (size_t)bx0 * BLK) * NCH;
#pragma unroll
    for (int r = 0; r < BLK; ++r) {
        const float* rp = base + (size_t)r * IMG_W * NCH;
#pragma unroll
        for (int q = 0; q < 3; ++q) {
            const float4 va = *(const float4*)(rp + q * 4);
            const float4 vb = *(const float4*)(rp + 12 + q * 4);
            xa[r * 12 + q * 4 + 0] = va.x; xa[r * 12 + q * 4 + 1] = va.y;
            xa[r * 12 + q * 4 + 2] = va.z; xa[r * 12 + q * 4 + 3] = va.w;
            xb[r * 12 + q * 4 + 0] = vb.x; xb[r * 12 + q * 4 + 1] = vb.y;
            xb[r * 12 + q * 4 + 2] = vb.z; xb[r * 12 + q * 4 + 3] = vb.w;
        }
    }

    // Norms (sequential FMA, same order as reference round)
    float na = 0.0f, nb = 0.0f;
#pragma unroll
    for (int j = 0; j < DD; ++j) na = fmaf(xa[j], xa[j], na);
#pragma unroll
    for (int j = 0; j < DD; ++j) nb = fmaf(xb[j], xb[j], nb);

    float bestA = __builtin_inff(), bestB = __builtin_inff();
    int ka = 0, kb = 0;

#pragma unroll 1
    for (int k = 0; k < NK; k += 2) {
        const float* c0 = cb + (size_t)k * DD;   // wave-uniform -> s_load
        const float* c1 = c0 + DD;
        float d00 = 0.0f, d01 = 0.0f, d10 = 0.0f, d11 = 0.0f;
#pragma unroll
        for (int j = 0; j < DD; ++j) {
            const float c0j = c0[j];
            const float c1j = c1[j];
            d00 = fmaf(xa[j], c0j, d00);
            d01 = fmaf(xa[j], c1j, d01);
            d10 = fmaf(xb[j], c0j, d10);
            d11 = fmaf(xb[j], c1j, d11);
        }
        // d = (norm - 2*dot) + cnorm ; fma(dot,-2,norm) == two-step exactly
        // since 2*dot is exact (power-of-two scale).
        const float cn0 = cnorm[k], cn1 = cnorm[k + 1];
        const float dA0 = fmaf(d00, -2.0f, na) + cn0;
        const float dA1 = fmaf(d01, -2.0f, na) + cn1;
        const float dB0 = fmaf(d10, -2.0f, nb) + cn0;
        const float dB1 = fmaf(d11, -2.0f, nb) + cn1;
        // ascending-k, strict < : first-occurrence argmin preserved
        if (dA0 < bestA) { bestA = dA0; ka = k; }
        if (dA1 < bestA) { bestA = dA1; ka = k + 1; }
        if (dB0 < bestB) { bestB = dB0; kb = k; }
        if (dB1 < bestB) { bestB = dB1; kb = k + 1; }
    }

    // Gather chosen codes and scatter back to image layout.
    const float* qa = cb + (size_t)ka * DD;
    const float* qb = cb + (size_t)kb * DD;
    float* ob = out + ((size_t)by * BLK * IMG_W + (size_t)bx0 * BLK) * NCH;
#pragma unroll
    for (int r = 0; r < BLK; ++r) {
        float* rp = ob + (size_t)r * IMG_W * NCH;
#pragma unroll
        for (int q = 0; q < 3; ++q) {
            *(float4*)(rp + q * 4)      = *(const float4*)(qa + r * 12 + q * 4);
            *(float4*)(rp + 12 + q * 4) = *(const float4*)(qb + r * 12 + q * 4);
        }
    }
}

extern "C" void kernel_launch(void* const* d_in, const int* in_sizes, int n_in,
                              void* d_out, int out_size, void* d_ws, size_t ws_size,
                              hipStream_t stream) {
    const float* img = (const float*)d_in[0];   // (2048, 2048, 3) fp32
    const float* cb  = (const float*)d_in[1];   // (1024, 16, 3) fp32
    float* out = (float*)d_out;                 // (2048, 2048, 3) fp32
    float* cnorm = (float*)d_ws;                // 1024 floats

    vq_cnorm_kernel<<<(NK + 255) / 256, 256, 0, stream>>>(cb, cnorm);
    vq_main_kernel<<<(NL / 2) / 256, 256, 0, stream>>>(img, cb, cnorm, out);
}

// Round 3
// 377.988 us; speedup vs baseline: 1.4045x; 1.2533x over previous
//
#include <hip/hip_runtime.h>

#define IMG_W 2048
#define NCH 3
#define BLK 4
#define NK 1024
#define DD 48              // BLK*BLK*NCH
#define WB 512             // blocks per image row
#define NL (WB * 512)      // 262144 blocks
#define CHUNK 256          // codes staged per LDS chunk (48 KB)
#define NCHUNK (NK / CHUNK)

// Kernel 0: cnorm[k] = sum_j cb[k][j]^2  (sequential fp32 FMA)
__global__ void vq_cnorm_kernel(const float* __restrict__ cb, float* __restrict__ cnorm) {
    int k = blockIdx.x * blockDim.x + threadIdx.x;
    if (k >= NK) return;
    const float* row = cb + k * DD;
    float s = 0.0f;
#pragma unroll
    for (int j = 0; j < DD; ++j) s = fmaf(row[j], row[j], s);
    cnorm[k] = s;
}

// 16 FMAs for one float4 slice Q: two codes (a,b) x two blocks (xa,xb).
// Per-accumulator j order is ascending -> matches reference rounding.
#define DOT_Q(Q) do {                                   \
        const float4 a = c0p[Q];                        \
        const float4 b = c1p[Q];                        \
        d00 = fmaf(xa_##Q.x, a.x, d00);                 \
        d00 = fmaf(xa_##Q.y, a.y, d00);                 \
        d00 = fmaf(xa_##Q.z, a.z, d00);                 \
        d00 = fmaf(xa_##Q.w, a.w, d00);                 \
        d01 = fmaf(xa_##Q.x, b.x, d01);                 \
        d01 = fmaf(xa_##Q.y, b.y, d01);                 \
        d01 = fmaf(xa_##Q.z, b.z, d01);                 \
        d01 = fmaf(xa_##Q.w, b.w, d01);                 \
        d10 = fmaf(xb_##Q.x, a.x, d10);                 \
        d10 = fmaf(xb_##Q.y, a.y, d10);                 \
        d10 = fmaf(xb_##Q.z, a.z, d10);                 \
        d10 = fmaf(xb_##Q.w, a.w, d10);                 \
        d11 = fmaf(xb_##Q.x, b.x, d11);                 \
        d11 = fmaf(xb_##Q.y, b.y, d11);                 \
        d11 = fmaf(xb_##Q.z, b.z, d11);                 \
        d11 = fmaf(xb_##Q.w, b.w, d11);                 \
    } while (0)

#define NORM_Q(Q) do {                                  \
        na = fmaf(xa_##Q.x, xa_##Q.x, na);              \
        na = fmaf(xa_##Q.y, xa_##Q.y, na);              \
        na = fmaf(xa_##Q.z, xa_##Q.z, na);              \
        na = fmaf(xa_##Q.w, xa_##Q.w, na);              \
        nb = fmaf(xb_##Q.x, xb_##Q.x, nb);              \
        nb = fmaf(xb_##Q.y, xb_##Q.y, nb);              \
        nb = fmaf(xb_##Q.z, xb_##Q.z, nb);              \
        nb = fmaf(xb_##Q.w, xb_##Q.w, nb);              \
    } while (0)

__global__ __launch_bounds__(256, 2) void vq_main_kernel(const float* __restrict__ img,
                                                         const float* __restrict__ cb,
                                                         const float* __restrict__ cnorm,
                                                         float* __restrict__ out) {
    __shared__ float4 lds[CHUNK * 12];   // 48 KB: 256 codes x 48 floats

    const int tid = threadIdx.x;
    const int t   = blockIdx.x * blockDim.x + tid;  // pair id, < NL/2
    const int by  = t >> 8;
    const int px  = t & 255;
    const int bx0 = px * 2;

    // ---- load both 4x4x3 blocks into NAMED float4 registers ----
    const float* base = img + ((size_t)by * BLK * IMG_W + (size_t)bx0 * BLK) * NCH;
    const float* rp0 = base;
    const float* rp1 = base + (size_t)IMG_W * NCH;
    const float* rp2 = base + (size_t)2 * IMG_W * NCH;
    const float* rp3 = base + (size_t)3 * IMG_W * NCH;

    float4 xa_0 = *(const float4*)(rp0 + 0), xa_1  = *(const float4*)(rp0 + 4), xa_2  = *(const float4*)(rp0 + 8);
    float4 xb_0 = *(const float4*)(rp0 + 12), xb_1 = *(const float4*)(rp0 + 16), xb_2 = *(const float4*)(rp0 + 20);
    float4 xa_3 = *(const float4*)(rp1 + 0), xa_4  = *(const float4*)(rp1 + 4), xa_5  = *(const float4*)(rp1 + 8);
    float4 xb_3 = *(const float4*)(rp1 + 12), xb_4 = *(const float4*)(rp1 + 16), xb_5 = *(const float4*)(rp1 + 20);
    float4 xa_6 = *(const float4*)(rp2 + 0), xa_7  = *(const float4*)(rp2 + 4), xa_8  = *(const float4*)(rp2 + 8);
    float4 xb_6 = *(const float4*)(rp2 + 12), xb_7 = *(const float4*)(rp2 + 16), xb_8 = *(const float4*)(rp2 + 20);
    float4 xa_9 = *(const float4*)(rp3 + 0), xa_10 = *(const float4*)(rp3 + 4), xa_11 = *(const float4*)(rp3 + 8);
    float4 xb_9 = *(const float4*)(rp3 + 12), xb_10 = *(const float4*)(rp3 + 16), xb_11 = *(const float4*)(rp3 + 20);

    // ---- norms (sequential FMA, ascending j) ----
    float na = 0.0f, nb = 0.0f;
    NORM_Q(0); NORM_Q(1); NORM_Q(2); NORM_Q(3); NORM_Q(4); NORM_Q(5);
    NORM_Q(6); NORM_Q(7); NORM_Q(8); NORM_Q(9); NORM_Q(10); NORM_Q(11);

    float bestA = __builtin_inff(), bestB = __builtin_inff();
    int ka = 0, kb = 0;

    for (int c = 0; c < NCHUNK; ++c) {
        __syncthreads();
        // stage 256 codes (48 KB) cooperatively, coalesced float4
        const float4* src = (const float4*)(cb + (size_t)c * CHUNK * DD);
#pragma unroll
        for (int p = 0; p < 12; ++p) lds[p * 256 + tid] = src[p * 256 + tid];
        __syncthreads();

#pragma unroll 1
        for (int kk = 0; kk < CHUNK; kk += 2) {
            const float4* c0p = &lds[kk * 12];   // uniform addr -> broadcast
            const float4* c1p = c0p + 12;
            const int k = c * CHUNK + kk;

            float d00 = 0.0f, d01 = 0.0f, d10 = 0.0f, d11 = 0.0f;
            DOT_Q(0); DOT_Q(1); DOT_Q(2); DOT_Q(3); DOT_Q(4); DOT_Q(5);
            DOT_Q(6); DOT_Q(7); DOT_Q(8); DOT_Q(9); DOT_Q(10); DOT_Q(11);

            const float cn0 = cnorm[k], cn1 = cnorm[k + 1];
            // fma(dot,-2,norm) == (norm - 2*dot) exactly (2*dot exact)
            const float dA0 = fmaf(d00, -2.0f, na) + cn0;
            const float dA1 = fmaf(d01, -2.0f, na) + cn1;
            const float dB0 = fmaf(d10, -2.0f, nb) + cn0;
            const float dB1 = fmaf(d11, -2.0f, nb) + cn1;

            // pairwise min, first-occurrence (strict <) semantics preserved
            const bool a1 = dA1 < dA0;
            const float wA = a1 ? dA1 : dA0;
            const int  wAk = a1 ? k + 1 : k;
            if (wA < bestA) { bestA = wA; ka = wAk; }
            const bool b1 = dB1 < dB0;
            const float wB = b1 ? dB1 : dB0;
            const int  wBk = b1 ? k + 1 : k;
            if (wB < bestB) { bestB = wB; kb = wBk; }
        }
    }

    // ---- gather chosen codes from global codebook, scatter to image layout ----
    const float4* qa = (const float4*)(cb + (size_t)ka * DD);
    const float4* qb = (const float4*)(cb + (size_t)kb * DD);
    float* ob = out + ((size_t)by * BLK * IMG_W + (size_t)bx0 * BLK) * NCH;
#pragma unroll
    for (int r = 0; r < BLK; ++r) {
        float* rp = ob + (size_t)r * IMG_W * NCH;
        *(float4*)(rp + 0)  = qa[r * 3 + 0];
        *(float4*)(rp + 4)  = qa[r * 3 + 1];
        *(float4*)(rp + 8)  = qa[r * 3 + 2];
        *(float4*)(rp + 12) = qb[r * 3 + 0];
        *(float4*)(rp + 16) = qb[r * 3 + 1];
        *(float4*)(rp + 20) = qb[r * 3 + 2];
    }
}

extern "C" void kernel_launch(void* const* d_in, const int* in_sizes, int n_in,
                              void* d_out, int out_size, void* d_ws, size_t ws_size,
                              hipStream_t stream) {
    const float* img = (const float*)d_in[0];   // (2048, 2048, 3) fp32
    const float* cb  = (const float*)d_in[1];   // (1024, 16, 3) fp32
    float* out = (float*)d_out;                 // (2048, 2048, 3) fp32
    float* cnorm = (float*)d_ws;                // 1024 floats

    vq_cnorm_kernel<<<(NK + 255) / 256, 256, 0, stream>>>(cb, cnorm);
    vq_main_kernel<<<(NL / 2) / 256, 256, 0, stream>>>(img, cb, cnorm, out);
}